// Round 19
// baseline (115.993 us; speedup 1.0000x reference)
//
#include <hip/hip_runtime.h>

#define CLAMP_MIN_F (-10.0f)
#define CLAMP_MAX_F (10.0f)
#define BATCH 8
#define SUP_LOG 8        // 256 nodes per super-bucket
#define SNODES 256
#define MAXS 512         // max supers (N <= 131072)
#define FIN_LOG 5        // 32 nodes per fine bucket
#define FNODES 32
#define ASTR 9           // LDS row stride (pad 8 -> 9)
#define EPB 16384        // edges per binning block
#define CH 2048          // records per LDS chunk
#define TB_BIN 1024
#define MAX4K 4096       // fine-bucket scan capacity

// ---- prep: transpose o_pre (B,N) -> (N,B); zero super totals ---------------
__global__ void prep_o_kernel(const float* __restrict__ o_pre,
                              float* __restrict__ o_preT,
                              unsigned* __restrict__ superTotal,
                              int N) {
    int n = blockIdx.x * blockDim.x + threadIdx.x;
    if (n < MAXS) superTotal[n] = 0u;
    if (n >= N) return;
    float o[BATCH];
    #pragma unroll
    for (int b = 0; b < BATCH; ++b) o[b] = o_pre[b * N + n];
    float4* op = (float4*)&o_preT[(size_t)n * BATCH];
    op[0] = make_float4(o[0], o[1], o[2], o[3]);
    op[1] = make_float4(o[4], o[5], o[6], o[7]);
}

// ---- pass 1: per-block FINE histogram; write rows; reserve super space -----
__global__ __launch_bounds__(TB_BIN)
void hist_fine_kernel(const int* __restrict__ dst,
                      unsigned* __restrict__ superTotal,
                      unsigned* __restrict__ histRows,   // (NB, 4096)
                      unsigned* __restrict__ offs0s,     // (NB, MAXS) relative
                      int edges) {
    __shared__ unsigned shf[MAX4K];   // 16 KB fine counters
    int bid = blockIdx.x, tid = threadIdx.x;
    for (int k = tid; k < MAX4K; k += blockDim.x) shf[k] = 0u;
    __syncthreads();
    int start = bid * EPB;
    int endE = min(edges, start + EPB);
    for (int i = start + tid; i < endE; i += blockDim.x)
        atomicAdd(&shf[((unsigned)dst[i]) >> FIN_LOG], 1u);
    __syncthreads();
    // write fine rows (coalesced)
    for (int k = tid; k < MAX4K; k += blockDim.x)
        histRows[(size_t)bid * MAX4K + k] = shf[k];
    // reserve super space (relative): super s = fine 8s..8s+7
    for (int s = tid; s < MAXS; s += blockDim.x) {
        unsigned c = 0;
        #pragma unroll
        for (int j = 0; j < 8; ++j) c += shf[8 * s + j];
        offs0s[(size_t)bid * MAXS + s] = c ? atomicAdd(&superTotal[s], c) : 0u;
    }
}

// ---- pass 2a: fine totals = column sums of histRows (unrolled for ILP) -----
__global__ void colsum_kernel(const unsigned* __restrict__ histRows,
                              unsigned* __restrict__ fineTotal,
                              int NB) {
    int k = blockIdx.x * blockDim.x + threadIdx.x;
    if (k >= MAX4K) return;
    unsigned s = 0;
    int b = 0;
    for (; b + 8 <= NB; b += 8) {
        unsigned v0 = histRows[(size_t)(b + 0) * MAX4K + k];
        unsigned v1 = histRows[(size_t)(b + 1) * MAX4K + k];
        unsigned v2 = histRows[(size_t)(b + 2) * MAX4K + k];
        unsigned v3 = histRows[(size_t)(b + 3) * MAX4K + k];
        unsigned v4 = histRows[(size_t)(b + 4) * MAX4K + k];
        unsigned v5 = histRows[(size_t)(b + 5) * MAX4K + k];
        unsigned v6 = histRows[(size_t)(b + 6) * MAX4K + k];
        unsigned v7 = histRows[(size_t)(b + 7) * MAX4K + k];
        s += v0 + v1 + v2 + v3 + v4 + v5 + v6 + v7;
    }
    for (; b < NB; ++b) s += histRows[(size_t)b * MAX4K + k];
    fineTotal[k] = s;
}

// ---- pass 2b: exclusive scan over fine totals (4096) -----------------------
__global__ void scan4_kernel(const unsigned* __restrict__ total,
                             unsigned* __restrict__ base,
                             int KPAD) {
    __shared__ unsigned s1[1024];
    __shared__ unsigned s2[1024];
    int t = threadIdx.x;
    unsigned v0 = (4 * t     < KPAD) ? total[4 * t]     : 0u;
    unsigned v1 = (4 * t + 1 < KPAD) ? total[4 * t + 1] : 0u;
    unsigned v2 = (4 * t + 2 < KPAD) ? total[4 * t + 2] : 0u;
    unsigned v3 = (4 * t + 3 < KPAD) ? total[4 * t + 3] : 0u;
    unsigned sum = v0 + v1 + v2 + v3;
    s1[t] = sum;
    __syncthreads();
    unsigned* cur = s1;
    unsigned* nxt = s2;
    for (int off = 1; off < 1024; off <<= 1) {
        unsigned x = cur[t];
        if (t >= off) x += cur[t - off];
        __syncthreads();
        nxt[t] = x;
        __syncthreads();
        unsigned* tmp = cur; cur = nxt; nxt = tmp;
    }
    unsigned incl = cur[t];
    unsigned excl = incl - sum;
    base[4 * t]     = excl;
    base[4 * t + 1] = excl + v0;
    base[4 * t + 2] = excl + v0 + v1;
    base[4 * t + 3] = excl + v0 + v1 + v2;
    if (t == 1023) base[MAX4K] = incl;
}

// ---- pass 3: LDS-staged scatter into SUPER-sorted records (coalesced) ------
// key = (dst & 255) << 17 | src   (src < 2^17); super base = fineBase[8s]
__global__ __launch_bounds__(TB_BIN)
void scatter1_kernel(const int* __restrict__ src,
                     const int* __restrict__ dst,
                     const float* __restrict__ w,
                     const unsigned* __restrict__ offs0s,
                     const unsigned* __restrict__ fineBase,
                     int2* __restrict__ recS,
                     int edges) {
    __shared__ int2 srec[CH];
    __shared__ unsigned short ssup[CH];
    __shared__ unsigned cnt[MAXS];
    __shared__ unsigned sstart[MAXS];
    __shared__ unsigned cursor[MAXS];
    __shared__ unsigned pa[MAXS];
    __shared__ unsigned pb[MAXS];
    int bid = blockIdx.x, tid = threadIdx.x;
    for (int s = tid; s < MAXS; s += blockDim.x)
        cursor[s] = fineBase[8 * s] + offs0s[(size_t)bid * MAXS + s];
    int start = bid * EPB;
    int endE = min(edges, start + EPB);
    for (int cs = start; cs < endE; cs += CH) {
        int m = min(CH, endE - cs);
        __syncthreads();
        for (int s = tid; s < MAXS; s += blockDim.x) cnt[s] = 0u;
        __syncthreads();
        int2 hrec[2]; unsigned hsup[2], hpos[2]; bool hv[2];
        #pragma unroll
        for (int j = 0; j < 2; ++j) {
            int i = tid + j * TB_BIN;
            hv[j] = (i < m);
            if (hv[j]) {
                int gi = cs + i;
                int d = dst[gi];
                unsigned key = (((unsigned)d & (SNODES - 1)) << 17) | (unsigned)src[gi];
                hrec[j] = make_int2((int)key, __float_as_int(w[gi]));
                hsup[j] = (unsigned)d >> SUP_LOG;
                hpos[j] = atomicAdd(&cnt[hsup[j]], 1u);
            }
        }
        __syncthreads();
        // exclusive prefix cnt -> sstart (512 wide)
        {
            unsigned* cur = pa;
            unsigned* nxt = pb;
            if (tid < MAXS) cur[tid] = cnt[tid];
            __syncthreads();
            for (int off = 1; off < MAXS; off <<= 1) {
                unsigned v = 0;
                if (tid < MAXS) { v = cur[tid]; if (tid >= off) v += cur[tid - off]; }
                __syncthreads();
                if (tid < MAXS) nxt[tid] = v;
                __syncthreads();
                unsigned* t2 = cur; cur = nxt; nxt = t2;
            }
            if (tid < MAXS) sstart[tid] = cur[tid] - cnt[tid];
            __syncthreads();
        }
        #pragma unroll
        for (int j = 0; j < 2; ++j) {
            if (hv[j]) {
                unsigned idx = sstart[hsup[j]] + hpos[j];
                srec[idx] = hrec[j];
                ssup[idx] = (unsigned short)hsup[j];
            }
        }
        __syncthreads();
        #pragma unroll
        for (int j = 0; j < 2; ++j) {
            int i = tid + j * TB_BIN;
            if (i < m) {
                unsigned sup = ssup[i];
                unsigned gpos = cursor[sup] + ((unsigned)i - sstart[sup]);
                recS[gpos] = srec[i];
            }
        }
        __syncthreads();
        for (int s = tid; s < MAXS; s += blockDim.x) cursor[s] += cnt[s];
    }
}

// ---- pass 4: per-super re-scatter into FINE-sorted records (coalesced) -----
// Block per super: 8 fine cursors (tiny working set), wave-ballot claims,
// LDS-staged sort, coalesced copy-out runs (~1000 records each).
__global__ __launch_bounds__(TB_BIN)
void scatter2_kernel(const int2* __restrict__ recS,
                     const unsigned* __restrict__ fineBase,
                     int2* __restrict__ recS2) {
    __shared__ int2 srec[CH];
    __shared__ unsigned char sfin[CH];
    __shared__ unsigned cnt8[8];
    __shared__ unsigned sstart8[9];
    __shared__ unsigned fineRun[8];
    int sb = blockIdx.x, tid = threadIdx.x;
    int lane = tid & 63;
    if (tid < 8) fineRun[tid] = fineBase[8 * sb + tid];
    unsigned r0 = fineBase[8 * sb];
    unsigned r1 = fineBase[8 * sb + 8];
    __syncthreads();
    for (unsigned cs = r0; cs < r1; cs += CH) {
        unsigned m = min((unsigned)CH, r1 - cs);
        if (tid < 8) cnt8[tid] = 0u;
        __syncthreads();
        int2 hrec[2]; unsigned hf[2], hpos[2]; bool hv[2];
        #pragma unroll
        for (int j = 0; j < 2; ++j) {
            unsigned i = (unsigned)tid + (unsigned)j * TB_BIN;
            hv[j] = (i < m);
            unsigned f = 8;   // invalid sentinel
            if (hv[j]) {
                hrec[j] = recS[cs + i];
                f = (((unsigned)hrec[j].x >> 17) >> FIN_LOG) & 7;
            }
            hf[j] = f;
            // wave-ballot aggregated claim: 8 atomics per wave
            for (unsigned ff = 0; ff < 8; ++ff) {
                unsigned long long mk = __ballot(f == ff);
                if (f == ff) {
                    int leader = (int)(__ffsll((long long)mk) - 1);
                    unsigned base = 0;
                    if (lane == leader)
                        base = atomicAdd(&cnt8[ff], (unsigned)__popcll(mk));
                    base = __shfl(base, leader, 64);
                    unsigned myoff = (unsigned)__popcll(mk & ((1ULL << lane) - 1ULL));
                    hpos[j] = base + myoff;
                }
            }
        }
        __syncthreads();
        if (tid == 0) {
            unsigned run = 0;
            #pragma unroll
            for (int fq = 0; fq < 8; ++fq) { sstart8[fq] = run; run += cnt8[fq]; }
            sstart8[8] = run;
        }
        __syncthreads();
        #pragma unroll
        for (int j = 0; j < 2; ++j) {
            if (hv[j]) {
                unsigned idx = sstart8[hf[j]] + hpos[j];
                srec[idx] = hrec[j];
                sfin[idx] = (unsigned char)hf[j];
            }
        }
        __syncthreads();
        #pragma unroll
        for (int j = 0; j < 2; ++j) {
            unsigned i = (unsigned)tid + (unsigned)j * TB_BIN;
            if (i < m) {
                unsigned f = sfin[i];
                recS2[fineRun[f] + (i - sstart8[f])] = srec[i];
            }
        }
        __syncthreads();
        if (tid < 8) fineRun[tid] += cnt8[tid];
    }
}

// ---- pass 5: R12-proven fine-bucket accumulate + fused finalize ------------
// 3125 blocks x 256 threads (8 blocks/CU). Phase A: claim+prefix+LDS sort.
// Phase B: group g (8 lanes) owns node g; register accumulate, En hoisted.
__global__ __launch_bounds__(256)
void accum12_kernel(const int2* __restrict__ recS2,
                    const unsigned* __restrict__ fineBase,
                    const float* __restrict__ o_preT,   // (N,B)
                    const float* __restrict__ E,        // (B,N)
                    const float* __restrict__ chem_in,  // (B,N)
                    const float* __restrict__ thr,
                    const float* __restrict__ decay,
                    float* __restrict__ new_o,          // (B,N)
                    float* __restrict__ new_e,          // (B,N)
                    int N) {
    __shared__ int2 srec[CH];                     // 16 KB
    __shared__ float e_lds[FNODES * ASTR];
    __shared__ float acc_st[FNODES * ASTR];
    __shared__ unsigned cnt[FNODES];
    __shared__ unsigned sstart[FNODES + 1];
    int k = blockIdx.x;
    int ns = k << FIN_LOG;
    int cnt_n = min(FNODES, N - ns);
    int tid = threadIdx.x;

    for (int i = tid; i < FNODES * BATCH; i += blockDim.x) {
        int b = i >> FIN_LOG;
        int n = i & (FNODES - 1);
        if (n < cnt_n) e_lds[n * ASTR + b] = E[(size_t)b * N + ns + n];
    }
    __syncthreads();

    int b = tid & 7;
    int g = tid >> 3;           // owned node (0..31)
    float En = e_lds[g * ASTR + b];
    float accv = 0.f;

    unsigned b0 = fineBase[k], b1 = fineBase[k + 1];
    for (unsigned cs = b0; cs < b1; cs += CH) {
        unsigned m = min((unsigned)CH, b1 - cs);
        if (tid < FNODES) cnt[tid] = 0u;
        __syncthreads();
        int2 hrec[8]; unsigned hmeta[8];
        #pragma unroll
        for (int j = 0; j < 8; ++j) {
            unsigned i = (unsigned)tid + (unsigned)j * 256u;
            if (i < m) {
                int2 rec = recS2[cs + i];
                unsigned dl = ((unsigned)rec.x >> 17) & (FNODES - 1);
                unsigned pos = atomicAdd(&cnt[dl], 1u);
                hrec[j] = rec;
                hmeta[j] = (dl << 16) | pos;
            } else {
                hmeta[j] = 0xFFFFFFFFu;
            }
        }
        __syncthreads();
        if (tid == 0) {
            unsigned run = 0;
            #pragma unroll
            for (int d = 0; d < FNODES; ++d) { sstart[d] = run; run += cnt[d]; }
            sstart[FNODES] = run;
        }
        __syncthreads();
        #pragma unroll
        for (int j = 0; j < 8; ++j) {
            if (hmeta[j] != 0xFFFFFFFFu) {
                unsigned dl = hmeta[j] >> 16;
                unsigned pos = hmeta[j] & 0xFFFFu;
                srec[sstart[dl] + pos] = hrec[j];
            }
        }
        __syncthreads();
        unsigned st = sstart[g];
        unsigned en = st + cnt[g];
        for (unsigned r = st; r < en; ++r) {
            int2 rec = srec[r];                        // broadcast in group
            unsigned si = (unsigned)rec.x & 0x1FFFFu;
            float Oj = o_preT[((size_t)si << 3) + b];  // merged 32B / group
            float wv = __int_as_float(rec.y);
            float df = Oj - En;
            float sg = (df > 0.f) ? 1.f : ((df < 0.f) ? -1.f : 0.f);
            accv += Oj * wv * sg;
        }
        __syncthreads();   // before cnt/srec reuse
    }

    acc_st[g * ASTR + b] = accv;
    __syncthreads();

    // fused finalize (coalesced global IO)
    for (int i = tid; i < FNODES * BATCH; i += blockDim.x) {
        int bb = i >> FIN_LOG;
        int n = i & (FNODES - 1);
        if (n >= cnt_n) continue;
        float e = e_lds[n * ASTR + bb];
        float S = e + chem_in[(size_t)bb * N + ns + n] + acc_st[n * ASTR + bb];
        S = fminf(fmaxf(S, CLAMP_MIN_F), CLAMP_MAX_F);
        float t  = thr[ns + n];
        float dc = decay[ns + n];
        bool gt = S > t;
        float no = fmaxf(S - t, 0.f);
        float ne = gt ? no : ((S == e) ? (e - dc) : S);
        new_o[(size_t)bb * N + ns + n] = no;
        new_e[(size_t)bb * N + ns + n] = ne;
    }
}

// ---------------- fallback: R3 atomic path ----------------------------------
__global__ void prep_kernel(const float* __restrict__ chem_in,
                            const float* __restrict__ o_pre,
                            const float* __restrict__ E,
                            float* __restrict__ chemT,
                            float* __restrict__ o_preT,
                            float* __restrict__ E_T,
                            int N) {
    int n = blockIdx.x * blockDim.x + threadIdx.x;
    if (n >= N) return;
    float c[BATCH], o[BATCH], ee[BATCH];
    #pragma unroll
    for (int b = 0; b < BATCH; ++b) {
        c[b]  = chem_in[b * N + n];
        o[b]  = o_pre[b * N + n];
        ee[b] = E[b * N + n];
    }
    float4* cp = (float4*)&chemT[(size_t)n * BATCH];
    cp[0] = make_float4(c[0], c[1], c[2], c[3]);
    cp[1] = make_float4(c[4], c[5], c[6], c[7]);
    float4* op = (float4*)&o_preT[(size_t)n * BATCH];
    op[0] = make_float4(o[0], o[1], o[2], o[3]);
    op[1] = make_float4(o[4], o[5], o[6], o[7]);
    float4* ep = (float4*)&E_T[(size_t)n * BATCH];
    ep[0] = make_float4(ee[0], ee[1], ee[2], ee[3]);
    ep[1] = make_float4(ee[4], ee[5], ee[6], ee[7]);
}
__global__ void edge_scatter_eb(const int* __restrict__ src,
                                const int* __restrict__ dst,
                                const float* __restrict__ w,
                                const float* __restrict__ o_preT,
                                const float* __restrict__ E_T,
                                float* __restrict__ chemT,
                                int edges) {
    int t = blockIdx.x * blockDim.x + threadIdx.x;
    int e = t >> 3;
    int b = t & 7;
    if (e >= edges) return;
    int s = src[e]; int d = dst[e]; float we = w[e];
    float Oj = o_preT[(size_t)s * BATCH + b];
    float En = E_T[(size_t)d * BATCH + b];
    float diff = Oj - En;
    float sg = (diff > 0.0f) ? 1.0f : ((diff < 0.0f) ? -1.0f : 0.0f);
    atomicAdd(&chemT[(size_t)d * BATCH + b], Oj * we * sg);
}
__global__ void finalize_nb(const float* __restrict__ E,
                            const float* __restrict__ chemT,
                            const float* __restrict__ thr,
                            const float* __restrict__ decay,
                            float* __restrict__ new_o,
                            float* __restrict__ new_e, int N) {
    int n = blockIdx.x * blockDim.x + threadIdx.x;
    if (n >= N) return;
    const float4* cp = (const float4*)&chemT[(size_t)n * BATCH];
    float4 c0 = cp[0], c1 = cp[1];
    float c[BATCH] = {c0.x, c0.y, c0.z, c0.w, c1.x, c1.y, c1.z, c1.w};
    float t = thr[n];
    float dc = decay[n];
    #pragma unroll
    for (int b = 0; b < BATCH; ++b) {
        int i = b * N + n;
        float e = E[i];
        float S = fminf(fmaxf(e + c[b], CLAMP_MIN_F), CLAMP_MAX_F);
        bool gt = S > t;
        float no = fmaxf(S - t, 0.0f);
        float ne = gt ? no : ((S == e) ? (e - dc) : S);
        new_o[i] = no;
        new_e[i] = ne;
    }
}

static inline size_t align256(size_t x) { return (x + 255) & ~(size_t)255; }

extern "C" void kernel_launch(void* const* d_in, const int* in_sizes, int n_in,
                              void* d_out, int out_size, void* d_ws, size_t ws_size,
                              hipStream_t stream) {
    const float* chem_influence = (const float*)d_in[0];
    const float* E              = (const float*)d_in[1];
    const int*   src            = (const int*)d_in[3];
    const int*   dst            = (const int*)d_in[4];
    const float* w              = (const float*)d_in[5];
    const float* o_pre          = (const float*)d_in[6];
    const float* threshold      = (const float*)d_in[7];
    const float* decay          = (const float*)d_in[8];

    const int edges = in_sizes[3];
    const int BN    = in_sizes[0];   // B * N
    const int N     = in_sizes[7];   // threshold is (N,)

    float* new_o = (float*)d_out;
    float* new_e = (float*)d_out + BN;

    const int TB = 256;
    int nblk = (N + TB - 1) / TB;

    const int NS = (N + SNODES - 1) >> SUP_LOG;   // super-buckets
    const int KF = (N + FNODES - 1) >> FIN_LOG;   // fine buckets
    const int NB = (edges + EPB - 1) / EPB;       // binning blocks

    // ws layout
    size_t off = 0;
    size_t opreT_off  = off; off += align256((size_t)BN * 4);
    size_t fbase_off  = off; off += align256((size_t)(MAX4K + 1) * 4);
    size_t ftot_off   = off; off += align256((size_t)MAX4K * 4);
    size_t stot_off   = off; off += align256((size_t)MAXS * 4);
    size_t hist_off   = off; off += align256((size_t)NB * MAX4K * 4);
    size_t offs0_off  = off; off += align256((size_t)NB * MAXS * 4);
    size_t rec_off    = off; off += align256((size_t)edges * 8);
    size_t rec2_off   = off; off += align256((size_t)edges * 8);
    size_t need = off;

    char* wsb = (char*)d_ws;

    if (NS <= MAXS && KF <= MAX4K - 1 && N <= (1 << 17) && ws_size >= need) {
        float*    o_preT   = (float*)(wsb + opreT_off);
        unsigned* fineBase = (unsigned*)(wsb + fbase_off);
        unsigned* fineTot  = (unsigned*)(wsb + ftot_off);
        unsigned* supTot   = (unsigned*)(wsb + stot_off);
        unsigned* histRows = (unsigned*)(wsb + hist_off);
        unsigned* offs0s   = (unsigned*)(wsb + offs0_off);
        int2*     recS     = (int2*)(wsb + rec_off);
        int2*     recS2    = (int2*)(wsb + rec2_off);

        prep_o_kernel<<<nblk, TB, 0, stream>>>(o_pre, o_preT, supTot, N);
        hist_fine_kernel<<<NB, TB_BIN, 0, stream>>>(dst, supTot, histRows,
                                                    offs0s, edges);
        colsum_kernel<<<MAX4K / TB, TB, 0, stream>>>(histRows, fineTot, NB);
        scan4_kernel<<<1, 1024, 0, stream>>>(fineTot, fineBase, MAX4K);
        scatter1_kernel<<<NB, TB_BIN, 0, stream>>>(src, dst, w, offs0s,
                                                   fineBase, recS, edges);
        scatter2_kernel<<<NS, TB_BIN, 0, stream>>>(recS, fineBase, recS2);
        accum12_kernel<<<KF, 256, 0, stream>>>(recS2, fineBase, o_preT, E,
                                               chem_influence, threshold, decay,
                                               new_o, new_e, N);
    } else if (ws_size >= 3 * (size_t)BN * 4) {
        float* chemT  = (float*)d_ws;
        float* o_preT = chemT + BN;
        float* E_T    = o_preT + BN;
        prep_kernel<<<nblk, TB, 0, stream>>>(chem_influence, o_pre, E,
                                             chemT, o_preT, E_T, N);
        long long ethreads = (long long)edges * BATCH;
        int gblk = (int)((ethreads + TB - 1) / TB);
        edge_scatter_eb<<<gblk, TB, 0, stream>>>(src, dst, w, o_preT, E_T,
                                                 chemT, edges);
        finalize_nb<<<nblk, TB, 0, stream>>>(E, chemT, threshold, decay,
                                             new_o, new_e, N);
    }
}

// Round 20
// 102.309 us; speedup vs baseline: 1.1337x; 1.1337x over previous
//
#include <hip/hip_runtime.h>

#define CLAMP_MIN_F (-10.0f)
#define CLAMP_MAX_F (10.0f)
#define BATCH 8
#define R_LOG 5          // 32 nodes per bucket
#define RNODES 32
#define ASTR 9           // LDS row stride (pad 8 -> 9)
#define EPB 32768        // edges per binning block (R20: 2x R12 -> 98 blocks,
                         // cursor working set 19.6MB < 32MB aggregate L2)
#define TB_BIN 1024      // threads for hist/scatter
#define MAX4K 4096       // scan capacity (K must be <= 4095)
#define SCHUNK 2048      // records per in-bucket sort chunk (16KB LDS)
#define MAXH (SCHUNK / 256)   // held records per thread per chunk

// ---- prep: transpose o_pre (B,N) -> (N,B); zero bucket totals --------------
__global__ void prep_o_kernel(const float* __restrict__ o_pre,
                              float* __restrict__ o_preT,
                              unsigned* __restrict__ total,
                              int N) {
    int n = blockIdx.x * blockDim.x + threadIdx.x;
    if (n < MAX4K) total[n] = 0u;
    if (n >= N) return;
    float o[BATCH];
    #pragma unroll
    for (int b = 0; b < BATCH; ++b) o[b] = o_pre[b * N + n];
    float4* op = (float4*)&o_preT[(size_t)n * BATCH];
    op[0] = make_float4(o[0], o[1], o[2], o[3]);
    op[1] = make_float4(o[4], o[5], o[6], o[7]);
}

// ---- pass 1: per-block histogram + direct space reservation ----------------
__global__ __launch_bounds__(TB_BIN)
void hist_reserve_kernel(const int* __restrict__ dst,
                         unsigned* __restrict__ total,
                         unsigned* __restrict__ offs0,
                         int edges, int KPAD) {
    __shared__ unsigned sh[MAX4K];
    int bid = blockIdx.x;
    for (int k = threadIdx.x; k < KPAD; k += blockDim.x) sh[k] = 0u;
    __syncthreads();
    int start = bid * EPB;
    int end = min(edges, start + EPB);
    for (int i = start + threadIdx.x; i < end; i += blockDim.x)
        atomicAdd(&sh[((unsigned)dst[i]) >> R_LOG], 1u);
    __syncthreads();
    for (int k = threadIdx.x; k < KPAD; k += blockDim.x) {
        unsigned c = sh[k];
        offs0[(size_t)bid * KPAD + k] = c ? atomicAdd(&total[k], c) : 0u;
    }
}

// ---- pass 2: exclusive scan over bucket totals (<=4096), 1024 thr x 4 ------
__global__ void scan4_kernel(const unsigned* __restrict__ total,
                             unsigned* __restrict__ base,
                             int KPAD) {
    __shared__ unsigned s1[1024];
    __shared__ unsigned s2[1024];
    int t = threadIdx.x;
    unsigned v0 = (4 * t     < KPAD) ? total[4 * t]     : 0u;
    unsigned v1 = (4 * t + 1 < KPAD) ? total[4 * t + 1] : 0u;
    unsigned v2 = (4 * t + 2 < KPAD) ? total[4 * t + 2] : 0u;
    unsigned v3 = (4 * t + 3 < KPAD) ? total[4 * t + 3] : 0u;
    unsigned sum = v0 + v1 + v2 + v3;
    s1[t] = sum;
    __syncthreads();
    unsigned* cur = s1;
    unsigned* nxt = s2;
    for (int off = 1; off < 1024; off <<= 1) {
        unsigned x = cur[t];
        if (t >= off) x += cur[t - off];
        __syncthreads();
        nxt[t] = x;
        __syncthreads();
        unsigned* tmp = cur; cur = nxt; nxt = tmp;
    }
    unsigned incl = cur[t];
    unsigned excl = incl - sum;
    base[4 * t]     = excl;
    base[4 * t + 1] = excl + v0;
    base[4 * t + 2] = excl + v0 + v1;
    base[4 * t + 3] = excl + v0 + v1 + v2;
    if (t == 1023) base[4096] = incl;
}

// ---- pass 3: scatter edges into 8B bucket-sorted records -------------------
// key = (dst_local:5 bits << 26) | src   (src < 2^26)
__global__ __launch_bounds__(TB_BIN)
void scatter_kernel(const int* __restrict__ src,
                    const int* __restrict__ dst,
                    const float* __restrict__ w,
                    const unsigned* __restrict__ offs0,
                    const unsigned* __restrict__ base,
                    int2* __restrict__ recS,
                    int edges, int KPAD) {
    __shared__ unsigned loffs[MAX4K];
    int bid = blockIdx.x;
    for (int k = threadIdx.x; k < KPAD; k += blockDim.x)
        loffs[k] = base[k] + offs0[(size_t)bid * KPAD + k];
    __syncthreads();
    int start = bid * EPB;
    int end = min(edges, start + EPB);
    for (int i = start + threadIdx.x; i < end; i += blockDim.x) {
        int d = dst[i];
        int s = src[i];
        float wv = w[i];
        unsigned k = ((unsigned)d) >> R_LOG;
        unsigned pos = atomicAdd(&loffs[k], 1u);
        unsigned key = (((unsigned)d & (RNODES - 1)) << 26) | (unsigned)s;
        recS[pos] = make_int2((int)key, __float_as_int(wv));
    }
}

// ---- pass 4: per-bucket counting-sort + register accumulate + finalize -----
// (R12-proven: <13 us with everything else) Phase A: thread-per-record claims
// a slot via LDS counter atomicAdd, scatters records dl-sorted into LDS.
// Phase B: 8-lane group g owns node dl=g; scans ITS records from LDS,
// accumulating in a REGISTER (zero accumulation atomics; En hoisted).
__global__ __launch_bounds__(256)
void accum_kernel(const int2* __restrict__ recS,
                  const unsigned* __restrict__ base,
                  const float* __restrict__ o_preT,   // (N,B)
                  const float* __restrict__ E,        // (B,N)
                  const float* __restrict__ chem_in,  // (B,N)
                  const float* __restrict__ thr,
                  const float* __restrict__ decay,
                  float* __restrict__ new_o,          // (B,N)
                  float* __restrict__ new_e,          // (B,N)
                  int N) {
    __shared__ int2 srec[SCHUNK];                 // 16 KB sorted records
    __shared__ float e_lds[RNODES * ASTR];
    __shared__ float acc_st[RNODES * ASTR];
    __shared__ unsigned cnt[RNODES];
    __shared__ unsigned sstart[RNODES + 1];
    int k = blockIdx.x;
    int ns = k << R_LOG;
    int cnt_n = min(RNODES, N - ns);
    int tid = threadIdx.x;

    for (int i = tid; i < RNODES * BATCH; i += blockDim.x) {
        int b = i >> R_LOG;
        int n = i & (RNODES - 1);
        if (n < cnt_n) e_lds[n * ASTR + b] = E[(size_t)b * N + ns + n];
    }
    __syncthreads();

    int b = tid & 7;            // batch lane
    int g = tid >> 3;           // owned node (0..31)
    float En = e_lds[g * ASTR + b];
    float accv = 0.f;

    unsigned b0 = base[k], b1 = base[k + 1];
    for (unsigned cs = b0; cs < b1; cs += SCHUNK) {
        unsigned m = min((unsigned)SCHUNK, b1 - cs);
        if (tid < RNODES) cnt[tid] = 0u;
        __syncthreads();

        // Phase A: claim slots
        int2 hrec[MAXH];
        unsigned hmeta[MAXH];
        #pragma unroll
        for (int j = 0; j < MAXH; ++j) {
            unsigned i = (unsigned)tid + (unsigned)j * blockDim.x;
            if (i < m) {
                int2 rec = recS[cs + i];
                unsigned dl = ((unsigned)rec.x >> 26) & (RNODES - 1);
                unsigned pos = atomicAdd(&cnt[dl], 1u);
                hrec[j] = rec;
                hmeta[j] = (dl << 16) | pos;
            } else {
                hmeta[j] = 0xFFFFFFFFu;
            }
        }
        __syncthreads();
        if (tid == 0) {
            unsigned run = 0;
            for (int d = 0; d < RNODES; ++d) { sstart[d] = run; run += cnt[d]; }
            sstart[RNODES] = run;
        }
        __syncthreads();
        // Phase A2: scatter into sorted LDS array
        #pragma unroll
        for (int j = 0; j < MAXH; ++j) {
            if (hmeta[j] != 0xFFFFFFFFu) {
                unsigned dl = hmeta[j] >> 16;
                unsigned pos = hmeta[j] & 0xFFFFu;
                srec[sstart[dl] + pos] = hrec[j];
            }
        }
        __syncthreads();

        // Phase B: group g scans its own records; register accumulate
        unsigned st = sstart[g];
        unsigned en = st + cnt[g];
        for (unsigned r = st; r < en; ++r) {
            int2 rec = srec[r];                        // broadcast in group
            unsigned s = (unsigned)rec.x & 0x3FFFFFFu;
            float Oj = o_preT[((size_t)s << 3) + b];   // merged 32B / group
            float wv = __int_as_float(rec.y);
            float df = Oj - En;
            float sg = (df > 0.f) ? 1.f : ((df < 0.f) ? -1.f : 0.f);
            accv += Oj * wv * sg;
        }
        __syncthreads();   // before cnt/srec reuse
    }

    acc_st[g * ASTR + b] = accv;
    __syncthreads();

    // fused finalize (coalesced global IO)
    for (int i = tid; i < RNODES * BATCH; i += blockDim.x) {
        int bb = i >> R_LOG;
        int n = i & (RNODES - 1);
        if (n >= cnt_n) continue;
        float e = e_lds[n * ASTR + bb];
        float S = e + chem_in[(size_t)bb * N + ns + n] + acc_st[n * ASTR + bb];
        S = fminf(fmaxf(S, CLAMP_MIN_F), CLAMP_MAX_F);
        float t  = thr[ns + n];
        float dc = decay[ns + n];
        bool gt = S > t;
        float no = fmaxf(S - t, 0.f);
        float ne = gt ? no : ((S == e) ? (e - dc) : S);
        new_o[(size_t)bb * N + ns + n] = no;
        new_e[(size_t)bb * N + ns + n] = ne;
    }
}

// ---------------- fallback: R3 atomic path ----------------------------------
__global__ void prep_kernel(const float* __restrict__ chem_in,
                            const float* __restrict__ o_pre,
                            const float* __restrict__ E,
                            float* __restrict__ chemT,
                            float* __restrict__ o_preT,
                            float* __restrict__ E_T,
                            int N) {
    int n = blockIdx.x * blockDim.x + threadIdx.x;
    if (n >= N) return;
    float c[BATCH], o[BATCH], ee[BATCH];
    #pragma unroll
    for (int b = 0; b < BATCH; ++b) {
        c[b]  = chem_in[b * N + n];
        o[b]  = o_pre[b * N + n];
        ee[b] = E[b * N + n];
    }
    float4* cp = (float4*)&chemT[(size_t)n * BATCH];
    cp[0] = make_float4(c[0], c[1], c[2], c[3]);
    cp[1] = make_float4(c[4], c[5], c[6], c[7]);
    float4* op = (float4*)&o_preT[(size_t)n * BATCH];
    op[0] = make_float4(o[0], o[1], o[2], o[3]);
    op[1] = make_float4(o[4], o[5], o[6], o[7]);
    float4* ep = (float4*)&E_T[(size_t)n * BATCH];
    ep[0] = make_float4(ee[0], ee[1], ee[2], ee[3]);
    ep[1] = make_float4(ee[4], ee[5], ee[6], ee[7]);
}
__global__ void edge_scatter_eb(const int* __restrict__ src,
                                const int* __restrict__ dst,
                                const float* __restrict__ w,
                                const float* __restrict__ o_preT,
                                const float* __restrict__ E_T,
                                float* __restrict__ chemT,
                                int edges) {
    int t = blockIdx.x * blockDim.x + threadIdx.x;
    int e = t >> 3;
    int b = t & 7;
    if (e >= edges) return;
    int s = src[e]; int d = dst[e]; float we = w[e];
    float Oj = o_preT[(size_t)s * BATCH + b];
    float En = E_T[(size_t)d * BATCH + b];
    float diff = Oj - En;
    float sg = (diff > 0.0f) ? 1.0f : ((diff < 0.0f) ? -1.0f : 0.0f);
    atomicAdd(&chemT[(size_t)d * BATCH + b], Oj * we * sg);
}
__global__ void finalize_nb(const float* __restrict__ E,
                            const float* __restrict__ chemT,
                            const float* __restrict__ thr,
                            const float* __restrict__ decay,
                            float* __restrict__ new_o,
                            float* __restrict__ new_e, int N) {
    int n = blockIdx.x * blockDim.x + threadIdx.x;
    if (n >= N) return;
    const float4* cp = (const float4*)&chemT[(size_t)n * BATCH];
    float4 c0 = cp[0], c1 = cp[1];
    float c[BATCH] = {c0.x, c0.y, c0.z, c0.w, c1.x, c1.y, c1.z, c1.w};
    float t = thr[n];
    float dc = decay[n];
    #pragma unroll
    for (int b = 0; b < BATCH; ++b) {
        int i = b * N + n;
        float e = E[i];
        float S = fminf(fmaxf(e + c[b], CLAMP_MIN_F), CLAMP_MAX_F);
        bool gt = S > t;
        float no = fmaxf(S - t, 0.0f);
        float ne = gt ? no : ((S == e) ? (e - dc) : S);
        new_o[i] = no;
        new_e[i] = ne;
    }
}

static inline size_t align256(size_t x) { return (x + 255) & ~(size_t)255; }

extern "C" void kernel_launch(void* const* d_in, const int* in_sizes, int n_in,
                              void* d_out, int out_size, void* d_ws, size_t ws_size,
                              hipStream_t stream) {
    const float* chem_influence = (const float*)d_in[0];
    const float* E              = (const float*)d_in[1];
    const int*   src            = (const int*)d_in[3];
    const int*   dst            = (const int*)d_in[4];
    const float* w              = (const float*)d_in[5];
    const float* o_pre          = (const float*)d_in[6];
    const float* threshold      = (const float*)d_in[7];
    const float* decay          = (const float*)d_in[8];

    const int edges = in_sizes[3];
    const int BN    = in_sizes[0];   // B * N
    const int N     = in_sizes[7];   // threshold is (N,)

    float* new_o = (float*)d_out;
    float* new_e = (float*)d_out + BN;

    const int TB = 256;
    int nblk = (N + TB - 1) / TB;

    const int K    = (N + RNODES - 1) >> R_LOG;        // buckets (32 nodes)
    const int KPAD = (K + 63) & ~63;
    const int NB   = (edges + EPB - 1) / EPB;          // binning blocks (98)

    // ws layout
    size_t off = 0;
    size_t opreT_off  = off; off += align256((size_t)BN * 4);
    size_t base_off   = off; off += align256((size_t)(MAX4K + 1) * 4);
    size_t total_off  = off; off += align256((size_t)MAX4K * 4);
    size_t offs0_off  = off; off += align256((size_t)NB * KPAD * 4);
    size_t rec_off    = off; off += align256((size_t)edges * 8);
    size_t need = off;

    char* wsb = (char*)d_ws;

    if (K <= MAX4K - 1 && ws_size >= need) {
        float*    o_preT = (float*)(wsb + opreT_off);
        unsigned* base   = (unsigned*)(wsb + base_off);
        unsigned* total  = (unsigned*)(wsb + total_off);
        unsigned* offs0  = (unsigned*)(wsb + offs0_off);
        int2*     recS   = (int2*)(wsb + rec_off);

        prep_o_kernel<<<nblk, TB, 0, stream>>>(o_pre, o_preT, total, N);
        hist_reserve_kernel<<<NB, TB_BIN, 0, stream>>>(dst, total, offs0, edges, KPAD);
        scan4_kernel<<<1, 1024, 0, stream>>>(total, base, KPAD);
        scatter_kernel<<<NB, TB_BIN, 0, stream>>>(src, dst, w, offs0, base, recS, edges, KPAD);
        accum_kernel<<<K, 256, 0, stream>>>(recS, base, o_preT, E,
                                            chem_influence, threshold, decay,
                                            new_o, new_e, N);
    } else if (ws_size >= 3 * (size_t)BN * 4) {
        float* chemT  = (float*)d_ws;
        float* o_preT = chemT + BN;
        float* E_T    = o_preT + BN;
        prep_kernel<<<nblk, TB, 0, stream>>>(chem_influence, o_pre, E,
                                             chemT, o_preT, E_T, N);
        long long ethreads = (long long)edges * BATCH;
        int gblk = (int)((ethreads + TB - 1) / TB);
        edge_scatter_eb<<<gblk, TB, 0, stream>>>(src, dst, w, o_preT, E_T,
                                                 chemT, edges);
        finalize_nb<<<nblk, TB, 0, stream>>>(E, chemT, threshold, decay,
                                             new_o, new_e, N);
    }
}